// Round 7
// baseline (277.254 us; speedup 1.0000x reference)
//
#include <hip/hip_runtime.h>

#define TOK 4096
#define HID 1024
#define NEXP 8
#define CAP 512
#define WSZ 1048576  // HID*HID

typedef _Float16 f16;
typedef f16 f16x8 __attribute__((ext_vector_type(8)));
typedef f16 f16x4 __attribute__((ext_vector_type(4)));
typedef f16 f16x2 __attribute__((ext_vector_type(2)));
typedef float f32x4 __attribute__((ext_vector_type(4)));

typedef const __attribute__((address_space(1))) void gvoid;
typedef __attribute__((address_space(3))) void lvoid;

__device__ __forceinline__ void gld16(const void* g, void* l) {
  __builtin_amdgcn_global_load_lds((gvoid*)g, (lvoid*)l, 16, 0, 0);
}

// ---------------------------------------------------------------------------
// MFMA f16 GEMM: tile 128x128, BK=64, 256 thr = 4 waves (2x2), wave-tile
// 64x64 (4x4 frags of 16x16x32) -> 0.5 ds_read_b128 per MFMA (m97 geometry).
// Grid 256 blocks, bijective XCD swizzle: XCD x owns by in [4x,4x+4) = one
// expert for expert GEMMs (2MB B panel L2-resident). LDS 64KB -> 2 blocks/CU.
// T4 counted-vmcnt 2-phase: stage(t+1)[8 insts/wave] -> s_waitcnt vmcnt(8)
// (tile t landed) -> barrier -> 32 MFMA -> barrier; tile t+1 loads remain in
// flight across both barriers.
// MODE 0: C[r][col] = v
// MODE 1: A gathered via rowmap (-1 -> zero row TOK), C plain
// MODE 2: C[rowmap[r]][col] = v * gmax[rowmap[r]]  (skip r with rowmap=-1)
// LDS rows 64 f16 (8 chunks of 16B) XOR-swizzled chunk^=(row&7) via
// pre-swizzled global source (global_load_lds writes linearly).
// ---------------------------------------------------------------------------
template<int MODE>
__global__ __launch_bounds__(256, 2) void gemm_h(
    const f16* __restrict__ A, const f16* __restrict__ Bt,
    const float* __restrict__ bias, f16* __restrict__ C,
    const int* __restrict__ rowmap, const float* __restrict__ gmax,
    int rowsPerExpert, long bStride, int biasStride)
{
  __shared__ f16 As[2][128 * 64];
  __shared__ f16 Bs[2][128 * 64];
  const int tid = threadIdx.x;
  const int w = tid >> 6, l = tid & 63;
  const int wr = w >> 1, wc = w & 1;

  // bijective XCD swizzle: XCD x owns by in [4x, 4x+4), all bx
  const int orig = blockIdx.x;                 // 0..255
  const int sw = (orig & 7) * 32 + (orig >> 3);
  const int bx = sw & 7, by = sw >> 3;
  const int e = (by * 128) / rowsPerExpert;

  const int lr = l >> 3;                    // row within 8-row staging inst
  const int chunkSw = ((l & 7) ^ lr) * 8;   // pre-swizzled k-chunk (f16 elems)

  // staging: wave w stages A rows [w*32, w*32+32) and B rows [w*32, w*32+32)
  const f16* pa[4];
  #pragma unroll
  for (int i = 0; i < 4; ++i) {
    int r = by * 128 + w * 32 + i * 8 + lr;
    long tok = r;
    if (MODE == 1) { int t = rowmap[r]; tok = (t < 0) ? (long)TOK : (long)t; }
    pa[i] = A + tok * HID + chunkSw;
  }
  const f16* pb = Bt + (size_t)e * bStride
                + (size_t)(bx * 128 + w * 32 + lr) * HID + chunkSw;

  f32x4 acc[4][4];
  #pragma unroll
  for (int i = 0; i < 4; ++i)
    #pragma unroll
    for (int j = 0; j < 4; ++j) acc[i][j] = (f32x4){0.f, 0.f, 0.f, 0.f};

  const int g = l >> 4, c = l & 15, sa = c & 7;

  // prologue: stage k=0 into buf 0 (8 insts/wave)
  {
    f16* ab = &As[0][(w * 32) * 64];
    f16* bb = &Bs[0][(w * 32) * 64];
    #pragma unroll
    for (int i = 0; i < 4; ++i) gld16(pa[i], ab + i * 8 * 64);
    #pragma unroll
    for (int i = 0; i < 4; ++i) gld16(pb + (size_t)(i * 8) * HID, bb + i * 8 * 64);
  }

  int cur = 0;
  for (int t = 0; t < 15; ++t) {
    {  // stage tile t+1 into buf cur^1 (8 loads/wave stay in flight)
      const int k0 = (t + 1) * 64;
      f16* ab = &As[cur ^ 1][(w * 32) * 64];
      f16* bb = &Bs[cur ^ 1][(w * 32) * 64];
      #pragma unroll
      for (int i = 0; i < 4; ++i) gld16(pa[i] + k0, ab + i * 8 * 64);
      #pragma unroll
      for (int i = 0; i < 4; ++i) gld16(pb + (size_t)(i * 8) * HID + k0, bb + i * 8 * 64);
    }
    asm volatile("s_waitcnt vmcnt(8)" ::: "memory");  // tile t landed
    asm volatile("s_barrier" ::: "memory");           // buf[cur] full for all
    __builtin_amdgcn_s_setprio(1);
    #pragma unroll
    for (int h = 0; h < 2; ++h) {
      const int q = ((h * 4 + g) ^ sa) * 8;
      f16x8 af[4], bf[4];
      #pragma unroll
      for (int mi = 0; mi < 4; ++mi)
        af[mi] = *(const f16x8*)&As[cur][(wr * 64 + mi * 16 + c) * 64 + q];
      #pragma unroll
      for (int ni = 0; ni < 4; ++ni)
        bf[ni] = *(const f16x8*)&Bs[cur][(wc * 64 + ni * 16 + c) * 64 + q];
      #pragma unroll
      for (int mi = 0; mi < 4; ++mi)
        #pragma unroll
        for (int ni = 0; ni < 4; ++ni)
          acc[mi][ni] = __builtin_amdgcn_mfma_f32_16x16x32_f16(
              af[mi], bf[ni], acc[mi][ni], 0, 0, 0);
    }
    __builtin_amdgcn_s_setprio(0);
    asm volatile("s_barrier" ::: "memory");  // buf[cur] free for overwrite
    cur ^= 1;
  }
  // final tile
  asm volatile("s_waitcnt vmcnt(0)" ::: "memory");
  asm volatile("s_barrier" ::: "memory");
  __builtin_amdgcn_s_setprio(1);
  #pragma unroll
  for (int h = 0; h < 2; ++h) {
    const int q = ((h * 4 + g) ^ sa) * 8;
    f16x8 af[4], bf[4];
    #pragma unroll
    for (int mi = 0; mi < 4; ++mi)
      af[mi] = *(const f16x8*)&As[cur][(wr * 64 + mi * 16 + c) * 64 + q];
    #pragma unroll
    for (int ni = 0; ni < 4; ++ni)
      bf[ni] = *(const f16x8*)&Bs[cur][(wc * 64 + ni * 16 + c) * 64 + q];
    #pragma unroll
    for (int mi = 0; mi < 4; ++mi)
      #pragma unroll
      for (int ni = 0; ni < 4; ++ni)
        acc[mi][ni] = __builtin_amdgcn_mfma_f32_16x16x32_f16(
            af[mi], bf[ni], acc[mi][ni], 0, 0, 0);
  }
  __builtin_amdgcn_s_setprio(0);

  // epilogue: D col = lane&15, row = (lane>>4)*4 + reg
  int tk[4][4];
  float gv[4][4];
  if (MODE == 2) {
    #pragma unroll
    for (int mi = 0; mi < 4; ++mi)
      #pragma unroll
      for (int rr = 0; rr < 4; ++rr) {
        int r = by * 128 + wr * 64 + mi * 16 + g * 4 + rr;
        int t = rowmap[r];
        tk[mi][rr] = t;
        gv[mi][rr] = (t >= 0) ? gmax[t] : 0.f;
      }
  }
  #pragma unroll
  for (int ni = 0; ni < 4; ++ni) {
    const int col = bx * 128 + wc * 64 + ni * 16 + c;
    const float bv = bias[(size_t)e * biasStride + col];
    #pragma unroll
    for (int mi = 0; mi < 4; ++mi) {
      #pragma unroll
      for (int rr = 0; rr < 4; ++rr) {
        const float v = acc[mi][ni][rr] + bv;
        if (MODE == 2) {
          if (tk[mi][rr] >= 0)
            C[(size_t)tk[mi][rr] * HID + col] = (f16)(v * gv[mi][rr]);
        } else {
          const int row = by * 128 + wr * 64 + mi * 16 + g * 4 + rr;
          C[(size_t)row * HID + col] = (f16)v;
        }
      }
    }
  }
}

// ---------------------------------------------------------------------------
// Transpose-cast ALL weights: z in [0,35): 0..2 -> w1,w2,w3; 3..10 -> e1w1;
// 11..18 -> e1w2; 19..26 -> e2w1; 27..34 -> e2w2.  [k][n] f32 -> [n][k] f16.
// Each WG: 64 n-cols x 256 k (4 k-tiles). All 16 float4 loads issued up-front
// (latency amortized 4x), then per-tile LDS transpose. Both LDS phases are
// 2-way bank aliasing (free).
// ---------------------------------------------------------------------------
__global__ __launch_bounds__(256, 4) void tcast(
    const float* __restrict__ w1, const float* __restrict__ w2,
    const float* __restrict__ w3,
    const float* __restrict__ g1a, const float* __restrict__ g1b,
    const float* __restrict__ g2a, const float* __restrict__ g2b,
    f16* __restrict__ dst)
{
  __shared__ float t[64][65];
  const int z = blockIdx.z;
  const float* src; int zl = 0;
  if (z == 0) src = w1;
  else if (z == 1) src = w2;
  else if (z == 2) src = w3;
  else if (z < 11) { src = g1a; zl = z - 3; }
  else if (z < 19) { src = g1b; zl = z - 11; }
  else if (z < 27) { src = g2a; zl = z - 19; }
  else             { src = g2b; zl = z - 27; }
  src += (size_t)zl * WSZ;
  f16* d = dst + (size_t)z * WSZ;

  const int tid = threadIdx.x;
  const int kb4 = blockIdx.y * 256, nb = blockIdx.x * 64;
  const int rr = tid >> 4, c4 = (tid & 15) * 4;

  float4 v[4][4];
  #pragma unroll
  for (int tt = 0; tt < 4; ++tt)
    #pragma unroll
    for (int p = 0; p < 4; ++p)
      v[tt][p] = *(const float4*)&src[(size_t)(kb4 + tt * 64 + p * 16 + rr) * HID + nb + c4];

  #pragma unroll
  for (int tt = 0; tt < 4; ++tt) {
    if (tt) __syncthreads();
    #pragma unroll
    for (int p = 0; p < 4; ++p) {
      t[p * 16 + rr][c4 + 0] = v[tt][p].x;
      t[p * 16 + rr][c4 + 1] = v[tt][p].y;
      t[p * 16 + rr][c4 + 2] = v[tt][p].z;
      t[p * 16 + rr][c4 + 3] = v[tt][p].w;
    }
    __syncthreads();
    #pragma unroll
    for (int half = 0; half < 2; ++half) {
      const int p = half * 256 + tid;
      const int n = p >> 3, kc = p & 7;
      f16x8 o;
      #pragma unroll
      for (int j = 0; j < 8; ++j) o[j] = (f16)t[kc * 8 + j][n];
      *(f16x8*)&d[(size_t)(nb + n) * HID + kb4 + tt * 64 + kc * 8] = o;
    }
  }
}

// ---------------------------------------------------------------------------
// prep: castx (x f32 -> X0 f16) + zero C1/C2 + zero the two gather pad rows
__global__ void prep(const float* __restrict__ x, f16* __restrict__ X0,
                     f16* __restrict__ c1, f16* __restrict__ c2,
                     f16* __restrict__ p1, f16* __restrict__ p2) {
  const size_t i = (size_t)blockIdx.x * 256 + threadIdx.x;  // 1048576 threads
  float4 v = *(const float4*)&x[i * 4];
  f16x4 o = {(f16)v.x, (f16)v.y, (f16)v.z, (f16)v.w};
  *(f16x4*)&X0[i * 4] = o;
  const f16x8 zz = {0, 0, 0, 0, 0, 0, 0, 0};
  if (i < 524288) { ((f16x8*)c1)[i] = zz; ((f16x8*)c2)[i] = zz; }
  if (i < 128)    { ((f16x8*)p1)[i] = zz; ((f16x8*)p2)[i] = zz; }
}

// ---------------------------------------------------------------------------
// Gating from f16 activations: 8 tokens/block, 32 lanes/token, f32 accum.
// ---------------------------------------------------------------------------
__global__ __launch_bounds__(256) void gate_kernel(
    const f16* __restrict__ act, const float* __restrict__ wg,
    int* __restrict__ idx, float* __restrict__ gmax)
{
  const int tid = threadIdx.x;
  const int tok = blockIdx.x * 8 + (tid >> 5);
  const int sl = tid & 31;
  const f16* row = act + (size_t)tok * HID + sl * 32;
  float xv[32];
  #pragma unroll
  for (int v = 0; v < 4; ++v) {
    f16x8 hv = *(const f16x8*)(row + v * 8);
    #pragma unroll
    for (int j = 0; j < 8; ++j) xv[v * 8 + j] = (float)hv[j];
  }
  float p[NEXP];
  #pragma unroll
  for (int e = 0; e < NEXP; ++e) p[e] = 0.f;
  const float* wr_ = wg + (size_t)(sl * 32) * NEXP;
  #pragma unroll
  for (int j = 0; j < 32; ++j) {
    #pragma unroll
    for (int e = 0; e < NEXP; ++e) p[e] += xv[j] * wr_[j * NEXP + e];
  }
  #pragma unroll
  for (int m = 1; m < 32; m <<= 1) {
    #pragma unroll
    for (int e = 0; e < NEXP; ++e) p[e] += __shfl_xor(p[e], m, 64);
  }
  if (sl == 0) {
    float mx = p[0]; int am = 0;
    #pragma unroll
    for (int e = 1; e < NEXP; ++e)
      if (p[e] > mx) { mx = p[e]; am = e; }
    float s = 0.f;
    #pragma unroll
    for (int e = 0; e < NEXP; ++e) s += expf(p[e] - mx);
    idx[tok] = am;
    gmax[tok] = 1.f / s;
  }
}

// ---------------------------------------------------------------------------
// Capacity scan (cumsum-of-one_hot semantics): wave e owns expert e.
// ---------------------------------------------------------------------------
__global__ __launch_bounds__(512) void scan_kernel(
    const int* __restrict__ idx, int* __restrict__ rowmap)
{
  __shared__ int sidx[TOK];
  const int tid = threadIdx.x;
  for (int i = tid; i < TOK; i += 512) sidx[i] = idx[i];
  for (int i = tid; i < NEXP * CAP; i += 512) rowmap[i] = -1;
  __syncthreads();
  const int wave = tid >> 6, lane = tid & 63;
  int running = 0;
  for (int ch = 0; ch < TOK / 64; ++ch) {
    int t = ch * 64 + lane;
    bool flag = (sidx[t] == wave);
    unsigned long long m = __ballot(flag);
    int pos = running + __popcll(m & ((1ull << lane) - 1ull));
    if (flag && pos < CAP) rowmap[wave * CAP + pos] = t;
    running += __popcll(m);
  }
}

// ---------------------------------------------------------------------------
// mean stage 1: partial[sc][b][h] = sum over 32 s of (a+c).  grid (2,8,16).
// ---------------------------------------------------------------------------
__global__ __launch_bounds__(256) void mean1_kernel(
    const f16* __restrict__ a, const f16* __restrict__ c,
    float* __restrict__ partial)
{
  const int h2 = blockIdx.x * 256 + threadIdx.x;  // 0..511
  const int b = blockIdx.y, sc = blockIdx.z;
  const f16x2* pa = (const f16x2*)(a + ((size_t)b * 512 + sc * 32) * HID) + h2;
  const f16x2* pc = (const f16x2*)(c + ((size_t)b * 512 + sc * 32) * HID) + h2;
  float a0 = 0.f, a1 = 0.f;
  #pragma unroll 4
  for (int s = 0; s < 32; ++s) {
    f16x2 va = pa[(size_t)s * 512];
    f16x2 vc = pc[(size_t)s * 512];
    a0 += (float)va[0] + (float)vc[0];
    a1 += (float)va[1] + (float)vc[1];
  }
  float* o = partial + ((size_t)sc * 8 + b) * HID;
  o[h2 * 2]     = a0;
  o[h2 * 2 + 1] = a1;
}

// mean stage 2: sent[b][h] = (1/512) sum over 16 sc.  grid (2,8).
__global__ __launch_bounds__(256) void mean2_kernel(
    const float* __restrict__ partial, float* __restrict__ sent)
{
  const int h2 = blockIdx.x * 256 + threadIdx.x;
  const int b = blockIdx.y;
  float a0 = 0.f, a1 = 0.f;
  #pragma unroll
  for (int sc = 0; sc < 16; ++sc) {
    const float* p = partial + ((size_t)sc * 8 + b) * HID + h2 * 2;
    a0 += p[0]; a1 += p[1];
  }
  sent[b * HID + h2 * 2]     = a0 * (1.f / 512.f);
  sent[b * HID + h2 * 2 + 1] = a1 * (1.f / 512.f);
}

__global__ __launch_bounds__(1024) void loss_kernel(
    const float* __restrict__ sent, const int* __restrict__ y,
    float* __restrict__ out)
{
  __shared__ float red[1024];
  float loss = 0.0f;
  for (int b = 0; b < 8; ++b) {
    float v = sent[b * HID + threadIdx.x];
    red[threadIdx.x] = v;
    __syncthreads();
    for (int s = 512; s > 0; s >>= 1) {
      if (threadIdx.x < s)
        red[threadIdx.x] = fmaxf(red[threadIdx.x], red[threadIdx.x + s]);
      __syncthreads();
    }
    float m = red[0];
    __syncthreads();
    red[threadIdx.x] = expf(v - m);
    __syncthreads();
    for (int s = 512; s > 0; s >>= 1) {
      if (threadIdx.x < s) red[threadIdx.x] += red[threadIdx.x + s];
      __syncthreads();
    }
    if (threadIdx.x == 0) {
      float lse = m + logf(red[0]);
      loss += -(sent[b * HID + y[b]] - lse);
    }
    __syncthreads();
  }
  if (threadIdx.x == 0) out[0] = loss * (1.0f / 8.0f);
}

// ---------------------------------------------------------------------------
extern "C" void kernel_launch(void* const* d_in, const int* in_sizes, int n_in,
                              void* d_out, int out_size, void* d_ws, size_t ws_size,
                              hipStream_t stream)
{
  const float* x    = (const float*)d_in[0];
  const int*   y    = (const int*)d_in[1];
  const float* w1   = (const float*)d_in[2];
  const float* b1   = (const float*)d_in[3];
  const float* w2   = (const float*)d_in[4];
  const float* b2   = (const float*)d_in[5];
  const float* w3   = (const float*)d_in[6];
  const float* b3   = (const float*)d_in[7];
  const float* wg1  = (const float*)d_in[8];
  const float* e1w1 = (const float*)d_in[9];
  const float* e1b1 = (const float*)d_in[10];
  const float* e1w2 = (const float*)d_in[11];
  const float* e1b2 = (const float*)d_in[12];
  const float* wg2  = (const float*)d_in[13];
  const float* e2w1 = (const float*)d_in[14];
  const float* e2b1 = (const float*)d_in[15];
  const float* e2w2 = (const float*)d_in[16];
  const float* e2b2 = (const float*)d_in[17];

  // workspace (~135 MB)
  f16* WT = (f16*)d_ws;                          // 35 x [1024][1024] f16
  f16* X0 = WT + (size_t)35 * WSZ;               // [4096][1024]
  f16* H  = X0 + (size_t)TOK * HID;              // [4097][1024] (pad row)
  f16* EA = H + (size_t)(TOK + 1) * HID;         // [4096][1024] expert hidden
  f16* C1 = EA + (size_t)TOK * HID;              // [4096][1024] combine1 out
  f16* M1 = C1 + (size_t)TOK * HID;              // [4097][1024] (pad row)
  f16* C2 = M1 + (size_t)(TOK + 1) * HID;        // [4096][1024] combine2 out
  f16* O  = C2 + (size_t)TOK * HID;              // [4096][1024] final proj
  float* gmax  = (float*)(O + (size_t)TOK * HID);
  int* idx     = (int*)(gmax + TOK);
  int* rowmap  = idx + TOK;
  float* sent  = (float*)(rowmap + TOK);
  float* partial = sent + 8 * HID;               // [16][8][1024] f32

  prep<<<4096, 256, 0, stream>>>(x, X0, C1, C2,
                                 H + (size_t)TOK * HID, M1 + (size_t)TOK * HID);
  tcast<<<dim3(16, 4, 35), 256, 0, stream>>>(w1, w2, w3, e1w1, e1w2, e2w1, e2w2, WT);

  // hidden = x @ w1 + b1
  gemm_h<0><<<256, 256, 0, stream>>>(X0, WT, b1, H, nullptr, nullptr, TOK, 0, 0);

  // ---- MoE layer 1 ----
  gate_kernel<<<512, 256, 0, stream>>>(H, wg1, idx, gmax);
  scan_kernel<<<1, 512, 0, stream>>>(idx, rowmap);
  gemm_h<1><<<256, 256, 0, stream>>>(H,  WT + (size_t)3 * WSZ,  e1b1, EA, rowmap, nullptr, CAP, WSZ, HID);
  gemm_h<2><<<256, 256, 0, stream>>>(EA, WT + (size_t)11 * WSZ, e1b2, C1, rowmap, gmax,    CAP, WSZ, HID);

  // out = moe1 @ w2 + b2
  gemm_h<0><<<256, 256, 0, stream>>>(C1, WT + (size_t)1 * WSZ, b2, M1, nullptr, nullptr, TOK, 0, 0);

  // ---- MoE layer 2 ----
  gate_kernel<<<512, 256, 0, stream>>>(M1, wg2, idx, gmax);
  scan_kernel<<<1, 512, 0, stream>>>(idx, rowmap);
  gemm_h<1><<<256, 256, 0, stream>>>(M1, WT + (size_t)19 * WSZ, e2b1, EA, rowmap, nullptr, CAP, WSZ, HID);
  gemm_h<2><<<256, 256, 0, stream>>>(EA, WT + (size_t)27 * WSZ, e2b2, C2, rowmap, gmax,    CAP, WSZ, HID);

  // out = moe2 @ w3 + b3
  gemm_h<0><<<256, 256, 0, stream>>>(C2, WT + (size_t)2 * WSZ, b3, O, nullptr, nullptr, TOK, 0, 0);

  // final reduction
  mean1_kernel<<<dim3(2, 8, 16), 256, 0, stream>>>(H, O, partial);
  mean2_kernel<<<dim3(2, 8), 256, 0, stream>>>(partial, sent);
  loss_kernel<<<1, 1024, 0, stream>>>(sent, y, (float*)d_out);
}

// Round 8
// 223.422 us; speedup vs baseline: 1.2409x; 1.2409x over previous
//
#include <hip/hip_runtime.h>

#define TOK 4096
#define HID 1024
#define NEXP 8
#define CAP 512
#define WSZ 1048576  // HID*HID

typedef _Float16 f16;
typedef f16 f16x8 __attribute__((ext_vector_type(8)));
typedef f16 f16x4 __attribute__((ext_vector_type(4)));
typedef f16 f16x2 __attribute__((ext_vector_type(2)));
typedef float f32x4 __attribute__((ext_vector_type(4)));

typedef const __attribute__((address_space(1))) void gvoid;
typedef __attribute__((address_space(3))) void lvoid;

__device__ __forceinline__ void gld16(const void* g, void* l) {
  __builtin_amdgcn_global_load_lds((gvoid*)g, (lvoid*)l, 16, 0, 0);
}

// ---------------------------------------------------------------------------
// Fused GEMM + weight-transpose kernel.
// Blocks [0, nGemm): MFMA f16 GEMM, round-6 proven geometry: tile 128x128,
//   BK=64, 512 thr = 8 waves (2 row x 4 col), wave-tile 64x32 (4x2 frags).
//   Bijective XCD swizzle (by quads -> one expert/XCD). T4 counted-vmcnt
//   2-phase: stage(t+1) -> s_waitcnt vmcnt(4) -> barrier -> MFMA -> barrier.
//   LDS rows 64 f16 XOR-swizzled chunk^=(row&7) via pre-swizzled global src.
// Blocks [nGemm, nGemm + nMat*128): transpose-cast of nMat contiguous
//   [1024][1024] f32 weight matrices (tsrc) -> [n][k] f16 (tdst). Each block:
//   128 n-cols x 64 k. Runs CONCURRENTLY with the gemm blocks -> the
//   memory-bound transpose hides under the compute-bound GEMM.
// MODE 0: C[r][col] = v
// MODE 1: A gathered via rowmap (-1 -> zero row TOK)
// MODE 2: C[rowmap[r]][col] = v * gmax[rowmap[r]]  (skip rowmap=-1)
// ---------------------------------------------------------------------------
template<int MODE>
__global__ __launch_bounds__(512, 1) void gemm_fused(
    const f16* __restrict__ A, const f16* __restrict__ Bt,
    const float* __restrict__ bias, f16* __restrict__ C,
    const int* __restrict__ rowmap, const float* __restrict__ gmax,
    int rowsPerExpert, long bStride, int biasStride,
    const float* __restrict__ tsrc, f16* __restrict__ tdst, int nGemm)
{
  __shared__ __align__(16) unsigned char smem[65536];
  const int tid = threadIdx.x;

  if ((int)blockIdx.x >= nGemm) {
    // ---------------- transpose-cast role ----------------
    float (*t)[65] = (float (*)[65])smem;   // [128][65] f32 = 33.3 KB
    const int tb = blockIdx.x - nGemm;
    const int mat = tb >> 7, t7 = tb & 127;
    const int nb = (t7 & 7) * 128, kb = (t7 >> 3) * 64;
    const float* src = tsrc + (size_t)mat * WSZ;
    f16* d = tdst + (size_t)mat * WSZ;
    const int half = tid >> 8, tl = tid & 255;
    const int rr = tl >> 4, c4 = (tl & 15) * 4;
    float (*th)[65] = t + half * 64;
    float4 v[4];
    #pragma unroll
    for (int p = 0; p < 4; ++p)
      v[p] = *(const float4*)&src[(size_t)(kb + p * 16 + rr) * HID + nb + half * 64 + c4];
    #pragma unroll
    for (int p = 0; p < 4; ++p) {
      th[p * 16 + rr][c4 + 0] = v[p].x;
      th[p * 16 + rr][c4 + 1] = v[p].y;
      th[p * 16 + rr][c4 + 2] = v[p].z;
      th[p * 16 + rr][c4 + 3] = v[p].w;
    }
    __syncthreads();
    #pragma unroll
    for (int it = 0; it < 2; ++it) {
      const int p = it * 256 + tl;
      const int n = p >> 3, kc = p & 7;
      f16x8 o;
      #pragma unroll
      for (int j = 0; j < 8; ++j) o[j] = (f16)th[kc * 8 + j][n];
      *(f16x8*)&d[(size_t)(nb + half * 64 + n) * HID + kb + kc * 8] = o;
    }
    return;
  }

  // ---------------- GEMM role ----------------
  f16* As0 = (f16*)smem;             // [2][128*64] f16
  f16* Bs0 = (f16*)(smem + 32768);   // [2][128*64] f16
  const int w = tid >> 6, l = tid & 63;
  const int wr = w >> 2, wc = w & 3;

  // bijective XCD swizzle: XCD x owns by in [4x, 4x+4), all bx
  const int orig = blockIdx.x;                 // 0..255
  const int sw = (orig & 7) * 32 + (orig >> 3);
  const int bx = sw & 7, by = sw >> 3;
  const int e = (by * 128) / rowsPerExpert;

  const int lr = l >> 3;                    // row within 8-row staging inst
  const int chunkSw = ((l & 7) ^ lr) * 8;   // pre-swizzled k-chunk (f16 elems)

  // staging: waves 0-3 -> A rows w*32.., waves 4-7 -> B rows (w-4)*32..
  const f16* pst[4];
  if (w < 4) {
    #pragma unroll
    for (int i = 0; i < 4; ++i) {
      int r = by * 128 + w * 32 + i * 8 + lr;
      long tok = r;
      if (MODE == 1) { int t = rowmap[r]; tok = (t < 0) ? (long)TOK : (long)t; }
      pst[i] = A + tok * HID + chunkSw;
    }
  } else {
    #pragma unroll
    for (int i = 0; i < 4; ++i)
      pst[i] = Bt + (size_t)e * bStride
             + (size_t)(bx * 128 + (w - 4) * 32 + i * 8 + lr) * HID + chunkSw;
  }

  f32x4 acc[4][2];
  #pragma unroll
  for (int i = 0; i < 4; ++i)
    #pragma unroll
    for (int j = 0; j < 2; ++j) acc[i][j] = (f32x4){0.f, 0.f, 0.f, 0.f};

  const int g = l >> 4, c = l & 15, sa = c & 7;

  // prologue: stage k=0 into buf 0
  {
    f16* db = (w < 4) ? As0 + (w * 32) * 64 : Bs0 + ((w - 4) * 32) * 64;
    #pragma unroll
    for (int i = 0; i < 4; ++i) gld16(pst[i], db + i * 8 * 64);
  }

  int cur = 0;
  for (int t = 0; t < 15; ++t) {
    {  // stage tile t+1 into buf cur^1 (4 loads/wave stay in flight)
      const int k0 = (t + 1) * 64;
      f16* db = (w < 4) ? As0 + ((cur ^ 1) * 8192) + (w * 32) * 64
                        : Bs0 + ((cur ^ 1) * 8192) + ((w - 4) * 32) * 64;
      #pragma unroll
      for (int i = 0; i < 4; ++i) gld16(pst[i] + k0, db + i * 8 * 64);
    }
    asm volatile("s_waitcnt vmcnt(4)" ::: "memory");  // tile t landed
    asm volatile("s_barrier" ::: "memory");           // buf[cur] full for all
    __builtin_amdgcn_s_setprio(1);
    #pragma unroll
    for (int h = 0; h < 2; ++h) {
      const int q = ((h * 4 + g) ^ sa) * 8;
      f16x8 af[4], bf[2];
      #pragma unroll
      for (int mi = 0; mi < 4; ++mi)
        af[mi] = *(const f16x8*)&As0[cur * 8192 + (wr * 64 + mi * 16 + c) * 64 + q];
      #pragma unroll
      for (int ni = 0; ni < 2; ++ni)
        bf[ni] = *(const f16x8*)&Bs0[cur * 8192 + (wc * 32 + ni * 16 + c) * 64 + q];
      #pragma unroll
      for (int mi = 0; mi < 4; ++mi)
        #pragma unroll
        for (int ni = 0; ni < 2; ++ni)
          acc[mi][ni] = __builtin_amdgcn_mfma_f32_16x16x32_f16(
              af[mi], bf[ni], acc[mi][ni], 0, 0, 0);
    }
    __builtin_amdgcn_s_setprio(0);
    asm volatile("s_barrier" ::: "memory");  // buf[cur] free for overwrite
    cur ^= 1;
  }
  // final tile
  asm volatile("s_waitcnt vmcnt(0)" ::: "memory");
  asm volatile("s_barrier" ::: "memory");
  __builtin_amdgcn_s_setprio(1);
  #pragma unroll
  for (int h = 0; h < 2; ++h) {
    const int q = ((h * 4 + g) ^ sa) * 8;
    f16x8 af[4], bf[2];
    #pragma unroll
    for (int mi = 0; mi < 4; ++mi)
      af[mi] = *(const f16x8*)&As0[cur * 8192 + (wr * 64 + mi * 16 + c) * 64 + q];
    #pragma unroll
    for (int ni = 0; ni < 2; ++ni)
      bf[ni] = *(const f16x8*)&Bs0[cur * 8192 + (wc * 32 + ni * 16 + c) * 64 + q];
    #pragma unroll
    for (int mi = 0; mi < 4; ++mi)
      #pragma unroll
      for (int ni = 0; ni < 2; ++ni)
        acc[mi][ni] = __builtin_amdgcn_mfma_f32_16x16x32_f16(
            af[mi], bf[ni], acc[mi][ni], 0, 0, 0);
  }
  __builtin_amdgcn_s_setprio(0);

  // epilogue: D col = lane&15, row = (lane>>4)*4 + reg
  int tk[4][4];
  float gv[4][4];
  if (MODE == 2) {
    #pragma unroll
    for (int mi = 0; mi < 4; ++mi)
      #pragma unroll
      for (int rr = 0; rr < 4; ++rr) {
        int r = by * 128 + wr * 64 + mi * 16 + g * 4 + rr;
        int t = rowmap[r];
        tk[mi][rr] = t;
        gv[mi][rr] = (t >= 0) ? gmax[t] : 0.f;
      }
  }
  #pragma unroll
  for (int ni = 0; ni < 2; ++ni) {
    const int col = bx * 128 + wc * 32 + ni * 16 + c;
    const float bv = bias[(size_t)e * biasStride + col];
    #pragma unroll
    for (int mi = 0; mi < 4; ++mi) {
      #pragma unroll
      for (int rr = 0; rr < 4; ++rr) {
        const float v = acc[mi][ni][rr] + bv;
        if (MODE == 2) {
          if (tk[mi][rr] >= 0)
            C[(size_t)tk[mi][rr] * HID + col] = (f16)(v * gv[mi][rr]);
        } else {
          const int row = by * 128 + wr * 64 + mi * 16 + g * 4 + rr;
          C[(size_t)row * HID + col] = (f16)v;
        }
      }
    }
  }
}

// ---------------------------------------------------------------------------
// Standalone transpose-cast for the 3 dense weights (w1,w2,w3).
// ---------------------------------------------------------------------------
__global__ __launch_bounds__(256, 8) void tcast3(
    const float* __restrict__ w1, const float* __restrict__ w2,
    const float* __restrict__ w3, f16* __restrict__ dst)
{
  __shared__ float t[64][65];
  const int z = blockIdx.z;
  const float* src = (z == 0) ? w1 : (z == 1) ? w2 : w3;
  f16* d = dst + (size_t)z * WSZ;
  const int tid = threadIdx.x;
  const int kb = blockIdx.y * 64, nb = blockIdx.x * 64;
  const int rr = tid >> 4, c4 = (tid & 15) * 4;
  float4 v[4];
  #pragma unroll
  for (int p = 0; p < 4; ++p)
    v[p] = *(const float4*)&src[(size_t)(kb + p * 16 + rr) * HID + nb + c4];
  #pragma unroll
  for (int p = 0; p < 4; ++p) {
    t[p * 16 + rr][c4 + 0] = v[p].x;
    t[p * 16 + rr][c4 + 1] = v[p].y;
    t[p * 16 + rr][c4 + 2] = v[p].z;
    t[p * 16 + rr][c4 + 3] = v[p].w;
  }
  __syncthreads();
  #pragma unroll
  for (int half = 0; half < 2; ++half) {
    const int p = half * 256 + tid;
    const int n = p >> 3, kc = p & 7;
    f16x8 o;
    #pragma unroll
    for (int j = 0; j < 8; ++j) o[j] = (f16)t[kc * 8 + j][n];
    *(f16x8*)&d[(size_t)(nb + n) * HID + kb + kc * 8] = o;
  }
}

// ---------------------------------------------------------------------------
// prep: castx (x f32 -> X0 f16) + zero C1/C2 + zero the two gather pad rows
__global__ void prep(const float* __restrict__ x, f16* __restrict__ X0,
                     f16* __restrict__ c1, f16* __restrict__ c2,
                     f16* __restrict__ p1, f16* __restrict__ p2) {
  const size_t i = (size_t)blockIdx.x * 256 + threadIdx.x;  // 1048576 threads
  float4 v = *(const float4*)&x[i * 4];
  f16x4 o = {(f16)v.x, (f16)v.y, (f16)v.z, (f16)v.w};
  *(f16x4*)&X0[i * 4] = o;
  const f16x8 zz = {0, 0, 0, 0, 0, 0, 0, 0};
  if (i < 524288) { ((f16x8*)c1)[i] = zz; ((f16x8*)c2)[i] = zz; }
  if (i < 128)    { ((f16x8*)p1)[i] = zz; ((f16x8*)p2)[i] = zz; }
}

// ---------------------------------------------------------------------------
// Gating from f16 activations: 8 tokens/block, 32 lanes/token, f32 accum.
// ---------------------------------------------------------------------------
__global__ __launch_bounds__(256) void gate_kernel(
    const f16* __restrict__ act, const float* __restrict__ wg,
    int* __restrict__ idx, float* __restrict__ gmax)
{
  const int tid = threadIdx.x;
  const int tok = blockIdx.x * 8 + (tid >> 5);
  const int sl = tid & 31;
  const f16* row = act + (size_t)tok * HID + sl * 32;
  float xv[32];
  #pragma unroll
  for (int v = 0; v < 4; ++v) {
    f16x8 hv = *(const f16x8*)(row + v * 8);
    #pragma unroll
    for (int j = 0; j < 8; ++j) xv[v * 8 + j] = (float)hv[j];
  }
  float p[NEXP];
  #pragma unroll
  for (int e = 0; e < NEXP; ++e) p[e] = 0.f;
  const float* wr_ = wg + (size_t)(sl * 32) * NEXP;
  #pragma unroll
  for (int j = 0; j < 32; ++j) {
    #pragma unroll
    for (int e = 0; e < NEXP; ++e) p[e] += xv[j] * wr_[j * NEXP + e];
  }
  #pragma unroll
  for (int m = 1; m < 32; m <<= 1) {
    #pragma unroll
    for (int e = 0; e < NEXP; ++e) p[e] += __shfl_xor(p[e], m, 64);
  }
  if (sl == 0) {
    float mx = p[0]; int am = 0;
    #pragma unroll
    for (int e = 1; e < NEXP; ++e)
      if (p[e] > mx) { mx = p[e]; am = e; }
    float s = 0.f;
    #pragma unroll
    for (int e = 0; e < NEXP; ++e) s += expf(p[e] - mx);
    idx[tok] = am;
    gmax[tok] = 1.f / s;
  }
}

// ---------------------------------------------------------------------------
// Capacity scan (cumsum-of-one_hot semantics): wave e owns expert e.
// ---------------------------------------------------------------------------
__global__ __launch_bounds__(512) void scan_kernel(
    const int* __restrict__ idx, int* __restrict__ rowmap)
{
  __shared__ int sidx[TOK];
  const int tid = threadIdx.x;
  for (int i = tid; i < TOK; i += 512) sidx[i] = idx[i];
  for (int i = tid; i < NEXP * CAP; i += 512) rowmap[i] = -1;
  __syncthreads();
  const int wave = tid >> 6, lane = tid & 63;
  int running = 0;
  for (int ch = 0; ch < TOK / 64; ++ch) {
    int t = ch * 64 + lane;
    bool flag = (sidx[t] == wave);
    unsigned long long m = __ballot(flag);
    int pos = running + __popcll(m & ((1ull << lane) - 1ull));
    if (flag && pos < CAP) rowmap[wave * CAP + pos] = t;
    running += __popcll(m);
  }
}

// ---------------------------------------------------------------------------
// mean stage 1: partial[sc][b][h] = sum over 32 s of (a+c).  grid (2,8,16).
// ---------------------------------------------------------------------------
__global__ __launch_bounds__(256) void mean1_kernel(
    const f16* __restrict__ a, const f16* __restrict__ c,
    float* __restrict__ partial)
{
  const int h2 = blockIdx.x * 256 + threadIdx.x;  // 0..511
  const int b = blockIdx.y, sc = blockIdx.z;
  const f16x2* pa = (const f16x2*)(a + ((size_t)b * 512 + sc * 32) * HID) + h2;
  const f16x2* pc = (const f16x2*)(c + ((size_t)b * 512 + sc * 32) * HID) + h2;
  float a0 = 0.f, a1 = 0.f;
  #pragma unroll 4
  for (int s = 0; s < 32; ++s) {
    f16x2 va = pa[(size_t)s * 512];
    f16x2 vc = pc[(size_t)s * 512];
    a0 += (float)va[0] + (float)vc[0];
    a1 += (float)va[1] + (float)vc[1];
  }
  float* o = partial + ((size_t)sc * 8 + b) * HID;
  o[h2 * 2]     = a0;
  o[h2 * 2 + 1] = a1;
}

// mean stage 2: sent[b][h] = (1/512) sum over 16 sc.  grid (2,8).
__global__ __launch_bounds__(256) void mean2_kernel(
    const float* __restrict__ partial, float* __restrict__ sent)
{
  const int h2 = blockIdx.x * 256 + threadIdx.x;
  const int b = blockIdx.y;
  float a0 = 0.f, a1 = 0.f;
  #pragma unroll
  for (int sc = 0; sc < 16; ++sc) {
    const float* p = partial + ((size_t)sc * 8 + b) * HID + h2 * 2;
    a0 += p[0]; a1 += p[1];
  }
  sent[b * HID + h2 * 2]     = a0 * (1.f / 512.f);
  sent[b * HID + h2 * 2 + 1] = a1 * (1.f / 512.f);
}

__global__ __launch_bounds__(1024) void loss_kernel(
    const float* __restrict__ sent, const int* __restrict__ y,
    float* __restrict__ out)
{
  __shared__ float red[1024];
  float loss = 0.0f;
  for (int b = 0; b < 8; ++b) {
    float v = sent[b * HID + threadIdx.x];
    red[threadIdx.x] = v;
    __syncthreads();
    for (int s = 512; s > 0; s >>= 1) {
      if (threadIdx.x < s)
        red[threadIdx.x] = fmaxf(red[threadIdx.x], red[threadIdx.x + s]);
      __syncthreads();
    }
    float m = red[0];
    __syncthreads();
    red[threadIdx.x] = expf(v - m);
    __syncthreads();
    for (int s = 512; s > 0; s >>= 1) {
      if (threadIdx.x < s) red[threadIdx.x] += red[threadIdx.x + s];
      __syncthreads();
    }
    if (threadIdx.x == 0) {
      float lse = m + logf(red[0]);
      loss += -(sent[b * HID + y[b]] - lse);
    }
    __syncthreads();
  }
  if (threadIdx.x == 0) out[0] = loss * (1.0f / 8.0f);
}

// ---------------------------------------------------------------------------
extern "C" void kernel_launch(void* const* d_in, const int* in_sizes, int n_in,
                              void* d_out, int out_size, void* d_ws, size_t ws_size,
                              hipStream_t stream)
{
  const float* x    = (const float*)d_in[0];
  const int*   y    = (const int*)d_in[1];
  const float* w1   = (const float*)d_in[2];
  const float* b1   = (const float*)d_in[3];
  const float* w2   = (const float*)d_in[4];
  const float* b2   = (const float*)d_in[5];
  const float* w3   = (const float*)d_in[6];
  const float* b3   = (const float*)d_in[7];
  const float* wg1  = (const float*)d_in[8];
  const float* e1w1 = (const float*)d_in[9];
  const float* e1b1 = (const float*)d_in[10];
  const float* e1w2 = (const float*)d_in[11];
  const float* e1b2 = (const float*)d_in[12];
  const float* wg2  = (const float*)d_in[13];
  const float* e2w1 = (const float*)d_in[14];
  const float* e2b1 = (const float*)d_in[15];
  const float* e2w2 = (const float*)d_in[16];
  const float* e2b2 = (const float*)d_in[17];

  // workspace (~135 MB)
  f16* WT = (f16*)d_ws;                          // 35 x [1024][1024] f16
  f16* X0 = WT + (size_t)35 * WSZ;               // [4096][1024]
  f16* H  = X0 + (size_t)TOK * HID;              // [4097][1024] (pad row)
  f16* EA = H + (size_t)(TOK + 1) * HID;         // [4096][1024] expert hidden
  f16* C1 = EA + (size_t)TOK * HID;              // [4096][1024] combine1 out
  f16* M1 = C1 + (size_t)TOK * HID;              // [4097][1024] (pad row)
  f16* C2 = M1 + (size_t)(TOK + 1) * HID;        // [4096][1024] combine2 out
  f16* O  = C2 + (size_t)TOK * HID;              // [4096][1024] final proj
  float* gmax  = (float*)(O + (size_t)TOK * HID);
  int* idx     = (int*)(gmax + TOK);
  int* rowmap  = idx + TOK;
  float* sent  = (float*)(rowmap + TOK);
  float* partial = sent + 8 * HID;               // [16][8][1024] f32

  f16* WTe1a = WT + (size_t)3 * WSZ;    // e1w1^T  (8 mats)
  f16* WTe1b = WT + (size_t)11 * WSZ;   // e1w2^T
  f16* WTe2a = WT + (size_t)19 * WSZ;   // e2w1^T
  f16* WTe2b = WT + (size_t)27 * WSZ;   // e2w2^T

  const int FUSED = 256 + 8 * 128;      // gemm blocks + 8 matrices x 128

  prep<<<4096, 256, 0, stream>>>(x, X0, C1, C2,
                                 H + (size_t)TOK * HID, M1 + (size_t)TOK * HID);
  tcast3<<<dim3(16, 16, 3), 256, 0, stream>>>(w1, w2, w3, WT);

  // hidden = x @ w1 + b1        (+ transpose e1w1)
  gemm_fused<0><<<FUSED, 512, 0, stream>>>(X0, WT, b1, H, nullptr, nullptr,
                                           TOK, 0, 0, e1w1, WTe1a, 256);

  // ---- MoE layer 1 ----
  gate_kernel<<<512, 256, 0, stream>>>(H, wg1, idx, gmax);
  scan_kernel<<<1, 512, 0, stream>>>(idx, rowmap);
  // EA = gather(H) @ e1w1 + e1b1   (+ transpose e1w2)
  gemm_fused<1><<<FUSED, 512, 0, stream>>>(H, WTe1a, e1b1, EA, rowmap, nullptr,
                                           CAP, WSZ, HID, e1w2, WTe1b, 256);
  // C1 = scatter(EA @ e1w2 + e1b2) (+ transpose e2w1)
  gemm_fused<2><<<FUSED, 512, 0, stream>>>(EA, WTe1b, e1b2, C1, rowmap, gmax,
                                           CAP, WSZ, HID, e2w1, WTe2a, 256);

  // M1 = C1 @ w2 + b2              (+ transpose e2w2)
  gemm_fused<0><<<FUSED, 512, 0, stream>>>(C1, WT + (size_t)1 * WSZ, b2, M1,
                                           nullptr, nullptr, TOK, 0, 0,
                                           e2w2, WTe2b, 256);

  // ---- MoE layer 2 ----
  gate_kernel<<<512, 256, 0, stream>>>(M1, wg2, idx, gmax);
  scan_kernel<<<1, 512, 0, stream>>>(idx, rowmap);
  gemm_fused<1><<<256, 512, 0, stream>>>(M1, WTe2a, e2b1, EA, rowmap, nullptr,
                                         CAP, WSZ, HID, w1, WT, 256);
  gemm_fused<2><<<256, 512, 0, stream>>>(EA, WTe2b, e2b2, C2, rowmap, gmax,
                                         CAP, WSZ, HID, w1, WT, 256);

  // O = C2 @ w3 + b3
  gemm_fused<0><<<256, 512, 0, stream>>>(C2, WT + (size_t)2 * WSZ, b3, O,
                                         nullptr, nullptr, TOK, 0, 0,
                                         w1, WT, 256);

  // final reduction
  mean1_kernel<<<dim3(2, 8, 16), 256, 0, stream>>>(H, O, partial);
  mean2_kernel<<<dim3(2, 8), 256, 0, stream>>>(partial, sent);
  loss_kernel<<<1, 1024, 0, stream>>>(sent, y, (float*)d_out);
}

// Round 9
// 218.382 us; speedup vs baseline: 1.2696x; 1.0231x over previous
//
#include <hip/hip_runtime.h>

#define TOK 4096
#define HID 1024
#define NEXP 8
#define CAP 512
#define WSZ 1048576  // HID*HID

typedef _Float16 f16;
typedef f16 f16x8 __attribute__((ext_vector_type(8)));
typedef f16 f16x4 __attribute__((ext_vector_type(4)));
typedef f16 f16x2 __attribute__((ext_vector_type(2)));
typedef float f32x4 __attribute__((ext_vector_type(4)));

typedef const __attribute__((address_space(1))) void gvoid;
typedef __attribute__((address_space(3))) void lvoid;

__device__ __forceinline__ void gld16(const void* g, void* l) {
  __builtin_amdgcn_global_load_lds((gvoid*)g, (lvoid*)l, 16, 0, 0);
}

// ---------------------------------------------------------------------------
// Fused GEMM + weight-transpose kernel (round-8 proven).
// Blocks [0, nGemm): MFMA f16 GEMM tile 128x128, BK=64, 512 thr = 8 waves,
//   wave-tile 64x32. Bijective XCD swizzle. Counted-vmcnt 2-phase pipeline.
// Blocks [nGemm, ...): transpose-cast tail blocks (128n x 64k per block),
//   co-resident with GEMM blocks (64KB + 33KB <= 160KB LDS).
// ---------------------------------------------------------------------------
template<int MODE>
__global__ __launch_bounds__(512, 1) void gemm_fused(
    const f16* __restrict__ A, const f16* __restrict__ Bt,
    const float* __restrict__ bias, f16* __restrict__ C,
    const int* __restrict__ rowmap, const float* __restrict__ gmax,
    int rowsPerExpert, long bStride, int biasStride,
    const float* __restrict__ tsrc, f16* __restrict__ tdst, int nGemm)
{
  __shared__ __align__(16) unsigned char smem[65536];
  const int tid = threadIdx.x;

  if ((int)blockIdx.x >= nGemm) {
    // ---------------- transpose-cast role ----------------
    float (*t)[65] = (float (*)[65])smem;   // [128][65] f32 = 33.3 KB
    const int tb = blockIdx.x - nGemm;
    const int mat = tb >> 7, t7 = tb & 127;
    const int nb = (t7 & 7) * 128, kb = (t7 >> 3) * 64;
    const float* src = tsrc + (size_t)mat * WSZ;
    f16* d = tdst + (size_t)mat * WSZ;
    const int half = tid >> 8, tl = tid & 255;
    const int rr = tl >> 4, c4 = (tl & 15) * 4;
    float (*th)[65] = t + half * 64;
    float4 v[4];
    #pragma unroll
    for (int p = 0; p < 4; ++p)
      v[p] = *(const float4*)&src[(size_t)(kb + p * 16 + rr) * HID + nb + half * 64 + c4];
    #pragma unroll
    for (int p = 0; p < 4; ++p) {
      th[p * 16 + rr][c4 + 0] = v[p].x;
      th[p * 16 + rr][c4 + 1] = v[p].y;
      th[p * 16 + rr][c4 + 2] = v[p].z;
      th[p * 16 + rr][c4 + 3] = v[p].w;
    }
    __syncthreads();
    #pragma unroll
    for (int it = 0; it < 2; ++it) {
      const int p = it * 256 + tl;
      const int n = p >> 3, kc = p & 7;
      f16x8 o;
      #pragma unroll
      for (int j = 0; j < 8; ++j) o[j] = (f16)th[kc * 8 + j][n];
      *(f16x8*)&d[(size_t)(nb + half * 64 + n) * HID + kb + kc * 8] = o;
    }
    return;
  }

  // ---------------- GEMM role ----------------
  f16* As0 = (f16*)smem;             // [2][128*64] f16
  f16* Bs0 = (f16*)(smem + 32768);   // [2][128*64] f16
  const int w = tid >> 6, l = tid & 63;
  const int wr = w >> 2, wc = w & 3;

  const int orig = blockIdx.x;                 // 0..255
  const int sw = (orig & 7) * 32 + (orig >> 3);
  const int bx = sw & 7, by = sw >> 3;
  const int e = (by * 128) / rowsPerExpert;

  const int lr = l >> 3;
  const int chunkSw = ((l & 7) ^ lr) * 8;

  const f16* pst[4];
  if (w < 4) {
    #pragma unroll
    for (int i = 0; i < 4; ++i) {
      int r = by * 128 + w * 32 + i * 8 + lr;
      long tok = r;
      if (MODE == 1) { int t = rowmap[r]; tok = (t < 0) ? (long)TOK : (long)t; }
      pst[i] = A + tok * HID + chunkSw;
    }
  } else {
    #pragma unroll
    for (int i = 0; i < 4; ++i)
      pst[i] = Bt + (size_t)e * bStride
             + (size_t)(bx * 128 + (w - 4) * 32 + i * 8 + lr) * HID + chunkSw;
  }

  f32x4 acc[4][2];
  #pragma unroll
  for (int i = 0; i < 4; ++i)
    #pragma unroll
    for (int j = 0; j < 2; ++j) acc[i][j] = (f32x4){0.f, 0.f, 0.f, 0.f};

  const int g = l >> 4, c = l & 15, sa = c & 7;

  {
    f16* db = (w < 4) ? As0 + (w * 32) * 64 : Bs0 + ((w - 4) * 32) * 64;
    #pragma unroll
    for (int i = 0; i < 4; ++i) gld16(pst[i], db + i * 8 * 64);
  }

  int cur = 0;
  for (int t = 0; t < 15; ++t) {
    {
      const int k0 = (t + 1) * 64;
      f16* db = (w < 4) ? As0 + ((cur ^ 1) * 8192) + (w * 32) * 64
                        : Bs0 + ((cur ^ 1) * 8192) + ((w - 4) * 32) * 64;
      #pragma unroll
      for (int i = 0; i < 4; ++i) gld16(pst[i] + k0, db + i * 8 * 64);
    }
    asm volatile("s_waitcnt vmcnt(4)" ::: "memory");
    asm volatile("s_barrier" ::: "memory");
    __builtin_amdgcn_s_setprio(1);
    #pragma unroll
    for (int h = 0; h < 2; ++h) {
      const int q = ((h * 4 + g) ^ sa) * 8;
      f16x8 af[4], bf[2];
      #pragma unroll
      for (int mi = 0; mi < 4; ++mi)
        af[mi] = *(const f16x8*)&As0[cur * 8192 + (wr * 64 + mi * 16 + c) * 64 + q];
      #pragma unroll
      for (int ni = 0; ni < 2; ++ni)
        bf[ni] = *(const f16x8*)&Bs0[cur * 8192 + (wc * 32 + ni * 16 + c) * 64 + q];
      #pragma unroll
      for (int mi = 0; mi < 4; ++mi)
        #pragma unroll
        for (int ni = 0; ni < 2; ++ni)
          acc[mi][ni] = __builtin_amdgcn_mfma_f32_16x16x32_f16(
              af[mi], bf[ni], acc[mi][ni], 0, 0, 0);
    }
    __builtin_amdgcn_s_setprio(0);
    asm volatile("s_barrier" ::: "memory");
    cur ^= 1;
  }
  asm volatile("s_waitcnt vmcnt(0)" ::: "memory");
  asm volatile("s_barrier" ::: "memory");
  __builtin_amdgcn_s_setprio(1);
  #pragma unroll
  for (int h = 0; h < 2; ++h) {
    const int q = ((h * 4 + g) ^ sa) * 8;
    f16x8 af[4], bf[2];
    #pragma unroll
    for (int mi = 0; mi < 4; ++mi)
      af[mi] = *(const f16x8*)&As0[cur * 8192 + (wr * 64 + mi * 16 + c) * 64 + q];
    #pragma unroll
    for (int ni = 0; ni < 2; ++ni)
      bf[ni] = *(const f16x8*)&Bs0[cur * 8192 + (wc * 32 + ni * 16 + c) * 64 + q];
    #pragma unroll
    for (int mi = 0; mi < 4; ++mi)
      #pragma unroll
      for (int ni = 0; ni < 2; ++ni)
        acc[mi][ni] = __builtin_amdgcn_mfma_f32_16x16x32_f16(
            af[mi], bf[ni], acc[mi][ni], 0, 0, 0);
  }
  __builtin_amdgcn_s_setprio(0);

  int tk[4][4];
  float gv[4][4];
  if (MODE == 2) {
    #pragma unroll
    for (int mi = 0; mi < 4; ++mi)
      #pragma unroll
      for (int rr = 0; rr < 4; ++rr) {
        int r = by * 128 + wr * 64 + mi * 16 + g * 4 + rr;
        int t = rowmap[r];
        tk[mi][rr] = t;
        gv[mi][rr] = (t >= 0) ? gmax[t] : 0.f;
      }
  }
  #pragma unroll
  for (int ni = 0; ni < 2; ++ni) {
    const int col = bx * 128 + wc * 32 + ni * 16 + c;
    const float bv = bias[(size_t)e * biasStride + col];
    #pragma unroll
    for (int mi = 0; mi < 4; ++mi) {
      #pragma unroll
      for (int rr = 0; rr < 4; ++rr) {
        const float v = acc[mi][ni][rr] + bv;
        if (MODE == 2) {
          if (tk[mi][rr] >= 0)
            C[(size_t)tk[mi][rr] * HID + col] = (f16)(v * gv[mi][rr]);
        } else {
          const int row = by * 128 + wr * 64 + mi * 16 + g * 4 + rr;
          C[(size_t)row * HID + col] = (f16)v;
        }
      }
    }
  }
}

// ---------------------------------------------------------------------------
// prep2: blocks [0,2048): cast x f32->f16, zero C1/C2 + pad rows (grid-stride)
//        blocks [2048, 2816): transpose-cast w1,w2,w3 (64x64 tiles)
// ---------------------------------------------------------------------------
__global__ __launch_bounds__(256) void prep2(
    const float* __restrict__ x, f16* __restrict__ X0,
    f16* __restrict__ c1, f16* __restrict__ c2,
    f16* __restrict__ p1, f16* __restrict__ p2,
    const float* __restrict__ w1, const float* __restrict__ w2,
    const float* __restrict__ w3, f16* __restrict__ WT)
{
  __shared__ float t[64][65];
  const int tid = threadIdx.x;
  if ((int)blockIdx.x < 2048) {
    const f16x8 zz = {0, 0, 0, 0, 0, 0, 0, 0};
    #pragma unroll
    for (int it = 0; it < 2; ++it) {
      const size_t i = (size_t)blockIdx.x * 256 + tid + (size_t)it * 524288;
      float4 v = *(const float4*)&x[i * 4];
      f16x4 o = {(f16)v.x, (f16)v.y, (f16)v.z, (f16)v.w};
      *(f16x4*)&X0[i * 4] = o;
      if (i < 524288) { ((f16x8*)c1)[i] = zz; ((f16x8*)c2)[i] = zz; }
      if (i < 128)    { ((f16x8*)p1)[i] = zz; ((f16x8*)p2)[i] = zz; }
    }
    return;
  }
  const int zb = blockIdx.x - 2048;
  const int z = zb >> 8, t7 = zb & 255;
  const float* src = (z == 0) ? w1 : (z == 1) ? w2 : w3;
  f16* d = WT + (size_t)z * WSZ;
  const int kb = (t7 >> 4) * 64, nb = (t7 & 15) * 64;
  const int rr = tid >> 4, c4 = (tid & 15) * 4;
  float4 v[4];
  #pragma unroll
  for (int p = 0; p < 4; ++p)
    v[p] = *(const float4*)&src[(size_t)(kb + p * 16 + rr) * HID + nb + c4];
  #pragma unroll
  for (int p = 0; p < 4; ++p) {
    t[p * 16 + rr][c4 + 0] = v[p].x;
    t[p * 16 + rr][c4 + 1] = v[p].y;
    t[p * 16 + rr][c4 + 2] = v[p].z;
    t[p * 16 + rr][c4 + 3] = v[p].w;
  }
  __syncthreads();
  #pragma unroll
  for (int half = 0; half < 2; ++half) {
    const int p = half * 256 + tid;
    const int n = p >> 3, kc = p & 7;
    f16x8 o;
    #pragma unroll
    for (int j = 0; j < 8; ++j) o[j] = (f16)t[kc * 8 + j][n];
    *(f16x8*)&d[(size_t)(nb + n) * HID + kb + kc * 8] = o;
  }
}

// ---------------------------------------------------------------------------
// Gating: 8 tokens/block, 32 lanes/token, f32 accum, float4 wg loads.
// ---------------------------------------------------------------------------
__global__ __launch_bounds__(256) void gate_kernel(
    const f16* __restrict__ act, const float* __restrict__ wg,
    int* __restrict__ idx, float* __restrict__ gmax)
{
  const int tid = threadIdx.x;
  const int tok = blockIdx.x * 8 + (tid >> 5);
  const int sl = tid & 31;
  const f16* row = act + (size_t)tok * HID + sl * 32;
  float xv[32];
  #pragma unroll
  for (int v = 0; v < 4; ++v) {
    f16x8 hv = *(const f16x8*)(row + v * 8);
    #pragma unroll
    for (int j = 0; j < 8; ++j) xv[v * 8 + j] = (float)hv[j];
  }
  float p[NEXP];
  #pragma unroll
  for (int e = 0; e < NEXP; ++e) p[e] = 0.f;
  const float4* w4 = (const float4*)(wg + (size_t)(sl * 32) * NEXP);
  #pragma unroll
  for (int j = 0; j < 32; ++j) {
    float4 lo = w4[2 * j], hi = w4[2 * j + 1];
    p[0] += xv[j] * lo.x; p[1] += xv[j] * lo.y;
    p[2] += xv[j] * lo.z; p[3] += xv[j] * lo.w;
    p[4] += xv[j] * hi.x; p[5] += xv[j] * hi.y;
    p[6] += xv[j] * hi.z; p[7] += xv[j] * hi.w;
  }
  #pragma unroll
  for (int m = 1; m < 32; m <<= 1) {
    #pragma unroll
    for (int e = 0; e < NEXP; ++e) p[e] += __shfl_xor(p[e], m, 64);
  }
  if (sl == 0) {
    float mx = p[0]; int am = 0;
    #pragma unroll
    for (int e = 1; e < NEXP; ++e)
      if (p[e] > mx) { mx = p[e]; am = e; }
    float s = 0.f;
    #pragma unroll
    for (int e = 0; e < NEXP; ++e) s += expf(p[e] - mx);
    idx[tok] = am;
    gmax[tok] = 1.f / s;
  }
}

// ---------------------------------------------------------------------------
__global__ __launch_bounds__(512) void scan_kernel(
    const int* __restrict__ idx, int* __restrict__ rowmap)
{
  __shared__ int sidx[TOK];
  const int tid = threadIdx.x;
  for (int i = tid; i < TOK; i += 512) sidx[i] = idx[i];
  for (int i = tid; i < NEXP * CAP; i += 512) rowmap[i] = -1;
  __syncthreads();
  const int wave = tid >> 6, lane = tid & 63;
  int running = 0;
  for (int ch = 0; ch < TOK / 64; ++ch) {
    int t = ch * 64 + lane;
    bool flag = (sidx[t] == wave);
    unsigned long long m = __ballot(flag);
    int pos = running + __popcll(m & ((1ull << lane) - 1ull));
    if (flag && pos < CAP) rowmap[wave * CAP + pos] = t;
    running += __popcll(m);
  }
}

// ---------------------------------------------------------------------------
// meanHC: partial sums over 32-s chunks of H and C2.  grid (2,8,16).
// ---------------------------------------------------------------------------
__global__ __launch_bounds__(256) void meanHC_kernel(
    const f16* __restrict__ Hb, const f16* __restrict__ C2b,
    float* __restrict__ pH, float* __restrict__ pC)
{
  const int h2 = blockIdx.x * 256 + threadIdx.x;  // 0..511
  const int b = blockIdx.y, sc = blockIdx.z;
  const f16x2* pa = (const f16x2*)(Hb + ((size_t)b * 512 + sc * 32) * HID) + h2;
  const f16x2* pc = (const f16x2*)(C2b + ((size_t)b * 512 + sc * 32) * HID) + h2;
  float a0 = 0.f, a1 = 0.f, c0 = 0.f, c1 = 0.f;
  #pragma unroll 4
  for (int s = 0; s < 32; ++s) {
    f16x2 va = pa[(size_t)s * 512];
    f16x2 vc = pc[(size_t)s * 512];
    a0 += (float)va[0]; a1 += (float)va[1];
    c0 += (float)vc[0]; c1 += (float)vc[1];
  }
  float* oh = pH + ((size_t)sc * 8 + b) * HID;
  float* oc = pC + ((size_t)sc * 8 + b) * HID;
  oh[h2 * 2] = a0; oh[h2 * 2 + 1] = a1;
  oc[h2 * 2] = c0; oc[h2 * 2 + 1] = c1;
}

// ---------------------------------------------------------------------------
// sent[b][col] = mean_s H + b3[col] + (mean_s C2) @ w3   (exact commute).
// grid 32 = 8 b x 4 col-chunks, 256 thr.  WT2 = w3^T [n][k] f16.
// ---------------------------------------------------------------------------
__global__ __launch_bounds__(256) void sent_kernel(
    const float* __restrict__ pH, const float* __restrict__ pC,
    const f16* __restrict__ WT2, const float* __restrict__ b3,
    float* __restrict__ sent)
{
  __shared__ float c2m[HID];
  const int tid = threadIdx.x;
  const int b = blockIdx.x >> 2, ch = blockIdx.x & 3;
  for (int kk = tid; kk < HID; kk += 256) {
    float s = 0.f;
    #pragma unroll
    for (int sc = 0; sc < 16; ++sc) s += pC[((size_t)sc * 8 + b) * HID + kk];
    c2m[kk] = s * (1.f / 512.f);
  }
  __syncthreads();
  const int col = ch * 256 + tid;
  float hv = 0.f;
  #pragma unroll
  for (int sc = 0; sc < 16; ++sc) hv += pH[((size_t)sc * 8 + b) * HID + col];
  float acc = hv * (1.f / 512.f) + b3[col];
  const f16* wrow = WT2 + (size_t)col * HID;
  for (int k0 = 0; k0 < HID; k0 += 8) {
    f16x8 wv = *(const f16x8*)(wrow + k0);
    #pragma unroll
    for (int j = 0; j < 8; ++j) acc += c2m[k0 + j] * (float)wv[j];
  }
  sent[b * HID + col] = acc;
}

// ---------------------------------------------------------------------------
// loss: shuffle-based block reductions (4 barriers per batch row).
// ---------------------------------------------------------------------------
__global__ __launch_bounds__(1024) void loss_kernel(
    const float* __restrict__ sent, const int* __restrict__ y,
    float* __restrict__ out)
{
  __shared__ float red[17];
  const int tid = threadIdx.x;
  const int wid = tid >> 6, lane = tid & 63;
  float loss = 0.0f;
  for (int b = 0; b < 8; ++b) {
    const float v = sent[b * HID + tid];
    float m = v;
    #pragma unroll
    for (int o = 32; o; o >>= 1) m = fmaxf(m, __shfl_xor(m, o, 64));
    if (lane == 0) red[wid] = m;
    __syncthreads();
    if (tid < 16) {
      float mm = red[tid];
      #pragma unroll
      for (int o = 8; o; o >>= 1) mm = fmaxf(mm, __shfl_xor(mm, o, 16));
      if (tid == 0) red[16] = mm;
    }
    __syncthreads();
    const float M = red[16];
    float s = expf(v - M);
    #pragma unroll
    for (int o = 32; o; o >>= 1) s += __shfl_xor(s, o, 64);
    __syncthreads();  // red[0..15] reuse
    if (lane == 0) red[wid] = s;
    __syncthreads();
    if (tid < 16) {
      float ss = red[tid];
      #pragma unroll
      for (int o = 8; o; o >>= 1) ss += __shfl_xor(ss, o, 16);
      if (tid == 0) red[16] = M + logf(ss);
    }
    __syncthreads();
    if (tid == 0) loss += -(sent[b * HID + y[b]] - red[16]);
    __syncthreads();
  }
  if (tid == 0) out[0] = loss * (1.0f / 8.0f);
}

// ---------------------------------------------------------------------------
extern "C" void kernel_launch(void* const* d_in, const int* in_sizes, int n_in,
                              void* d_out, int out_size, void* d_ws, size_t ws_size,
                              hipStream_t stream)
{
  const float* x    = (const float*)d_in[0];
  const int*   y    = (const int*)d_in[1];
  const float* w1   = (const float*)d_in[2];
  const float* b1   = (const float*)d_in[3];
  const float* w2   = (const float*)d_in[4];
  const float* b2   = (const float*)d_in[5];
  const float* w3   = (const float*)d_in[6];
  const float* b3   = (const float*)d_in[7];
  const float* wg1  = (const float*)d_in[8];
  const float* e1w1 = (const float*)d_in[9];
  const float* e1b1 = (const float*)d_in[10];
  const float* e1w2 = (const float*)d_in[11];
  const float* e1b2 = (const float*)d_in[12];
  const float* wg2  = (const float*)d_in[13];
  const float* e2w1 = (const float*)d_in[14];
  const float* e2b1 = (const float*)d_in[15];
  const float* e2w2 = (const float*)d_in[16];
  const float* e2b2 = (const float*)d_in[17];

  // workspace (~136 MB)
  f16* WT = (f16*)d_ws;                          // 35 x [1024][1024] f16
  f16* X0 = WT + (size_t)35 * WSZ;               // [4096][1024]
  f16* H  = X0 + (size_t)TOK * HID;              // [4097][1024] (pad row)
  f16* EA = H + (size_t)(TOK + 1) * HID;         // [4096][1024]
  f16* C1 = EA + (size_t)TOK * HID;              // [4096][1024]
  f16* M1 = C1 + (size_t)TOK * HID;              // [4097][1024] (pad row)
  f16* C2 = M1 + (size_t)(TOK + 1) * HID;        // [4096][1024]
  float* gmax  = (float*)(C2 + (size_t)TOK * HID);
  int* idx     = (int*)(gmax + TOK);
  int* rowmap  = idx + TOK;
  float* sent  = (float*)(rowmap + TOK);
  float* pH    = sent + 8 * HID;                 // [16][8][1024] f32
  float* pC    = pH + 16 * 8 * HID;              // [16][8][1024] f32

  f16* WTe1a = WT + (size_t)3 * WSZ;
  f16* WTe1b = WT + (size_t)11 * WSZ;
  f16* WTe2a = WT + (size_t)19 * WSZ;
  f16* WTe2b = WT + (size_t)27 * WSZ;

  const int FUSED = 256 + 8 * 128;

  // prep (x cast + zeros) + dense-weight transposes, one dispatch
  prep2<<<2816, 256, 0, stream>>>(x, X0, C1, C2,
                                  H + (size_t)TOK * HID, M1 + (size_t)TOK * HID,
                                  w1, w2, w3, WT);

  // hidden = x @ w1 + b1        (+ transpose e1w1)
  gemm_fused<0><<<FUSED, 512, 0, stream>>>(X0, WT, b1, H, nullptr, nullptr,
                                           TOK, 0, 0, e1w1, WTe1a, 256);

  // ---- MoE layer 1 ----
  gate_kernel<<<512, 256, 0, stream>>>(H, wg1, idx, gmax);
  scan_kernel<<<1, 512, 0, stream>>>(idx, rowmap);
  gemm_fused<1><<<FUSED, 512, 0, stream>>>(H, WTe1a, e1b1, EA, rowmap, nullptr,
                                           CAP, WSZ, HID, e1w2, WTe1b, 256);
  gemm_fused<2><<<FUSED, 512, 0, stream>>>(EA, WTe1b, e1b2, C1, rowmap, gmax,
                                           CAP, WSZ, HID, e2w1, WTe2a, 256);

  // M1 = C1 @ w2 + b2              (+ transpose e2w2)
  gemm_fused<0><<<FUSED, 512, 0, stream>>>(C1, WT + (size_t)1 * WSZ, b2, M1,
                                           nullptr, nullptr, TOK, 0, 0,
                                           e2w2, WTe2b, 256);

  // ---- MoE layer 2 ----
  gate_kernel<<<512, 256, 0, stream>>>(M1, wg2, idx, gmax);
  scan_kernel<<<1, 512, 0, stream>>>(idx, rowmap);
  gemm_fused<1><<<256, 512, 0, stream>>>(M1, WTe2a, e2b1, EA, rowmap, nullptr,
                                         CAP, WSZ, HID, w1, WT, 256);
  gemm_fused<2><<<256, 512, 0, stream>>>(EA, WTe2b, e2b2, C2, rowmap, gmax,
                                         CAP, WSZ, HID, w1, WT, 256);

  // final: sent = mean_s(H) + mean_s(C2) @ w3 + b3  (mean commutes with w3)
  meanHC_kernel<<<dim3(2, 8, 16), 256, 0, stream>>>(H, C2, pH, pC);
  sent_kernel<<<32, 256, 0, stream>>>(pH, pC, WT + (size_t)2 * WSZ, b3, sent);
  loss_kernel<<<1, 1024, 0, stream>>>(sent, y, (float*)d_out);
}